// Round 8
// baseline (504.169 us; speedup 1.0000x reference)
//
#include <hip/hip_runtime.h>
#include <math.h>

#define B_  4
#define S_  2048
#define D_  1024
#define H_  16
#define HD_ 64
#define DF_ 4096
#define M_  (B_*S_)   // 8192 rows

typedef unsigned short ushort_t;
typedef __bf16 bf16x8 __attribute__((ext_vector_type(8)));
typedef float  f32x4  __attribute__((ext_vector_type(4)));
typedef unsigned u32x4 __attribute__((ext_vector_type(4)));

#define FA_SCALE 0.18033688011112042f  // (1/8) * log2(e)

__device__ __forceinline__ ushort_t f2bf(float f) {
  union { float f; unsigned u; } v; v.f = f;
  unsigned r = v.u + 0x7FFFu + ((v.u >> 16) & 1u);
  return (ushort_t)(r >> 16);
}

__device__ __forceinline__ float bf2f(ushort_t u) {
  union { unsigned u; float f; } v; v.u = ((unsigned)u) << 16; return v.f;
}

// round-half-up bf16 pack of two floats -> u32 (lo = a, hi = b), 3 VALU ops
__device__ __forceinline__ unsigned pack_bf2(float a, float b) {
  union { float f; unsigned u; } ua, ub; ua.f = a; ub.f = b;
  return __builtin_amdgcn_perm(ub.u + 0x8000u, ua.u + 0x8000u, 0x07060302u);
}

__device__ __forceinline__ float fexp2(float x) {
#if __has_builtin(__builtin_amdgcn_exp2f)
  return __builtin_amdgcn_exp2f(x);
#else
  return __expf(x * 0.6931471805599453f);
#endif
}

// tanh-form GELU via exp2+rcp: ~5 VALU ops
__device__ __forceinline__ float fgelu(float x) {
  float e = fexp2(x * fmaf(x * x, -0.10295358f, -2.30221510f));
  return x * __builtin_amdgcn_rcpf(1.0f + e);
}

__device__ __forceinline__ void gload16(const void* g, void* l) {
  __builtin_amdgcn_global_load_lds(
      (const __attribute__((address_space(1))) void*)g,
      (__attribute__((address_space(3))) void*)l, 16, 0, 0);
}

// raw barrier with compiler memory fence (no vmcnt drain)
#define BARM() do { asm volatile("" ::: "memory"); \
                    __builtin_amdgcn_s_barrier();  \
                    asm volatile("" ::: "memory"); } while (0)
#define LGKM0() asm volatile("s_waitcnt lgkmcnt(0)" ::: "memory")

// ======== fused prep: 6 weight transposes (fp32->bf16^T, 64x64 tiles) + LN1 ========
struct PrepArgs {
  const float* w4src[4]; ushort_t* w4dst[4];
  const float* W1; ushort_t* W1T;
  const float* W2; ushort_t* W2T;
  const float* x; const float* g; const float* b; ushort_t* xn;
};

__global__ __launch_bounds__(256) void prep_kernel(PrepArgs p) {
  __shared__ float tile[64][65];
  __shared__ float sh[8];
  const int bid = blockIdx.x;
  const int t = threadIdx.x;
  if (bid < 3072) {
    const float* in; ushort_t* out; int R, C, bx, by;
    if (bid < 1024) {
      int j = bid >> 8, tt = bid & 255;
      in = p.w4src[j]; out = p.w4dst[j]; R = D_; C = D_; bx = tt & 15; by = tt >> 4;
    } else if (bid < 2048) {
      int tt = bid - 1024;
      in = p.W1; out = p.W1T; R = D_; C = DF_; bx = tt & 63; by = tt >> 6;
    } else {
      int tt = bid - 2048;
      in = p.W2; out = p.W2T; R = DF_; C = D_; bx = tt & 15; by = tt >> 4;
    }
    int r0 = by * 64, c0 = bx * 64;
    int lcol = t & 63, lrow = t >> 6;
    #pragma unroll
    for (int i = 0; i < 16; ++i)
      tile[lrow + 4 * i][lcol] = in[(size_t)(r0 + lrow + 4 * i) * C + c0 + lcol];
    __syncthreads();
    int l32 = t & 31, hw = t >> 5;
    #pragma unroll
    for (int i = 0; i < 8; ++i) {
      int c = hw + 8 * i;
      unsigned v = pack_bf2(tile[2 * l32][c], tile[2 * l32 + 1][c]);
      *(unsigned*)(out + (size_t)(c0 + c) * R + r0 + 2 * l32) = v;
    }
  } else {
    // LN1 row (fp32 in -> bf16 out)
    int row = bid - 3072;
    float4 v = ((const float4*)(p.x + (size_t)row * D_))[t];
    float s  = v.x + v.y + v.z + v.w;
    float ss = v.x*v.x + v.y*v.y + v.z*v.z + v.w*v.w;
    #pragma unroll
    for (int off = 32; off > 0; off >>= 1) {
      s  += __shfl_down(s, off);
      ss += __shfl_down(ss, off);
    }
    int w = t >> 6, lane = t & 63;
    if (lane == 0) { sh[w] = s; sh[4 + w] = ss; }
    __syncthreads();
    if (t == 0) {
      float a  = sh[0] + sh[1] + sh[2] + sh[3];
      float a2 = sh[4] + sh[5] + sh[6] + sh[7];
      float mean = a * (1.0f / D_);
      float var  = a2 * (1.0f / D_) - mean * mean;
      sh[0] = mean; sh[1] = rsqrtf(var + 1e-5f);
    }
    __syncthreads();
    float mean = sh[0], rstd = sh[1];
    float4 gv = ((const float4*)p.g)[t];
    float4 bv = ((const float4*)p.b)[t];
    ushort4 o;
    o.x = f2bf((v.x - mean) * rstd * gv.x + bv.x);
    o.y = f2bf((v.y - mean) * rstd * gv.y + bv.y);
    o.z = f2bf((v.z - mean) * rstd * gv.z + bv.z);
    o.w = f2bf((v.w - mean) * rstd * gv.w + bv.w);
    ((ushort4*)(p.xn + (size_t)row * D_))[t] = o;
  }
}

// ---------------- layernorm row(1024) -> bf16 (bf16 input) ----------------
template <int BF_IN>
__global__ __launch_bounds__(256) void ln_kernel(
    const void* __restrict__ xv, const float* __restrict__ g,
    const float* __restrict__ b, ushort_t* __restrict__ out) {
  int row = blockIdx.x;
  int t = threadIdx.x;
  float4 v;
  if constexpr (BF_IN) {
    ushort4 raw = ((const ushort4*)((const ushort_t*)xv + (size_t)row * D_))[t];
    v.x = bf2f(raw.x); v.y = bf2f(raw.y); v.z = bf2f(raw.z); v.w = bf2f(raw.w);
  } else {
    v = ((const float4*)((const float*)xv + (size_t)row * D_))[t];
  }
  float s  = v.x + v.y + v.z + v.w;
  float ss = v.x*v.x + v.y*v.y + v.z*v.z + v.w*v.w;
  #pragma unroll
  for (int off = 32; off > 0; off >>= 1) {
    s  += __shfl_down(s, off);
    ss += __shfl_down(ss, off);
  }
  __shared__ float sh[8];
  int w = t >> 6, lane = t & 63;
  if (lane == 0) { sh[w] = s; sh[4 + w] = ss; }
  __syncthreads();
  if (t == 0) {
    float a  = sh[0] + sh[1] + sh[2] + sh[3];
    float a2 = sh[4] + sh[5] + sh[6] + sh[7];
    float mean = a * (1.0f / D_);
    float var  = a2 * (1.0f / D_) - mean * mean;
    sh[0] = mean; sh[1] = rsqrtf(var + 1e-5f);
  }
  __syncthreads();
  float mean = sh[0], rstd = sh[1];
  float4 gv = ((const float4*)g)[t];
  float4 bv = ((const float4*)b)[t];
  ushort4 o;
  o.x = f2bf((v.x - mean) * rstd * gv.x + bv.x);
  o.y = f2bf((v.y - mean) * rstd * gv.y + bv.y);
  o.z = f2bf((v.z - mean) * rstd * gv.z + bv.z);
  o.w = f2bf((v.w - mean) * rstd * gv.w + bv.w);
  ((ushort4*)(out + (size_t)row * D_))[t] = o;
}

// ================= GEMM 128x128, BK=32, 4 waves, 32KB LDS, 4-5 blocks/CU ==========
// m97-exact structure (R0-verified): __syncthreads pipeline, gsw/rsw swizzle
// (2-way bank aliasing = free). High residency is the mechanism: with 4+ blocks/CU
// the other blocks' MFMA covers this block's barrier/vmcnt drains (m114).
// Used for QKV (MODE 5) and FFN1 (MODE 3) where the grid allows >= 4 blocks/CU.
template <int MODE>
__global__ __launch_bounds__(256, 4) void gemmK32(
    const ushort_t* __restrict__ A, const ushort_t* __restrict__ BT,
    const float* __restrict__ b0, const float* __restrict__ b1,
    const float* __restrict__ b2, const float* __restrict__ resF,
    const ushort_t* __restrict__ resB,
    float* __restrict__ outF, ushort_t* __restrict__ o0,
    ushort_t* __restrict__ o1, ushort_t* __restrict__ o2,
    int M, int N, int K) {
  __shared__ __align__(16) ushort_t lsA[2][128 * 32];
  __shared__ __align__(16) ushort_t lsB[2][128 * 32];
  const int t = threadIdx.x;
  const int lane = t & 63, w = t >> 6;          // 4 waves
  const int wy = w >> 1, wx = w & 1;
  const int q8 = lane >> 4, l16 = lane & 15;

  const int nX = gridDim.x;
  const int lin = blockIdx.y * nX + blockIdx.x;
  const int cpx = (nX * gridDim.y) >> 3;   // nwg % 8 == 0 at all call sites
  const int L = (lin & 7) * cpx + (lin >> 3);
  const int n0 = (L % nX) * 128;
  const int m0 = (L / nX) * 128;

  const int gsw = ((lane & 3) - (lane >> 3)) & 3;
  const int rsw = (q8 + (l16 >> 1)) & 3;

  const ushort_t* Ab = A  + (size_t)(m0 + (t >> 2)) * K + gsw * 8;
  const ushort_t* Bb = BT + (size_t)(n0 + (t >> 2)) * K + gsw * 8;

  auto stage = [&](int k0, int buf) {
    #pragma unroll
    for (int i = 0; i < 2; ++i) {
      gload16(Ab + 64 * (size_t)K * i + k0, lsA[buf] + (i * 256 + w * 64) * 8);
      gload16(Bb + 64 * (size_t)K * i + k0, lsB[buf] + (i * 256 + w * 64) * 8);
    }
  };

  f32x4 acc[4][4] = {};
  const int nIter = K >> 5;
  stage(0, 0);
  for (int it = 0; it < nIter; ++it) {
    __syncthreads();
    const int cur = it & 1;
    if (it + 1 < nIter) stage((it + 1) * 32, cur ^ 1);
    bf16x8 af[4], bfr[4];
    #pragma unroll
    for (int mi = 0; mi < 4; ++mi)
      af[mi] = *(const bf16x8*)(lsA[cur] + (wy * 64 + mi * 16 + l16) * 32 + rsw * 8);
    #pragma unroll
    for (int ni = 0; ni < 4; ++ni)
      bfr[ni] = *(const bf16x8*)(lsB[cur] + (wx * 64 + ni * 16 + l16) * 32 + rsw * 8);
    __builtin_amdgcn_s_setprio(1);
    #pragma unroll
    for (int mi = 0; mi < 4; ++mi)
      #pragma unroll
      for (int ni = 0; ni < 4; ++ni)
        acc[mi][ni] = __builtin_amdgcn_mfma_f32_16x16x32_bf16(bfr[ni], af[mi], acc[mi][ni], 0, 0, 0);
    __builtin_amdgcn_s_setprio(0);
  }

  // ---- epilogues: acc[mi][ni]; m = m0+wy*64+mi*16+l16, n = n0+wx*64+ni*16+q8*4
  if constexpr (MODE == 5) {
    const int kind = n0 >> 10;
    const float* bp = (kind == 0) ? b0 : (kind == 1) ? b1 : b2;
    ushort_t* dst = (kind == 0) ? o0 : (kind == 1) ? o1 : o2;
    #pragma unroll
    for (int ni = 0; ni < 4; ++ni) {
      int nn = (n0 & 1023) + wx * 64 + ni * 16 + q8 * 4;
      int h = nn >> 6, hd = nn & 63;
      float4 bb = *(const float4*)(bp + nn);
      #pragma unroll
      for (int mi = 0; mi < 4; ++mi) {
        int m = m0 + wy * 64 + mi * 16 + l16;
        int b = m >> 11, s = m & (S_ - 1);
        f32x4 a = acc[mi][ni];
        float v0 = a[0] + bb.x, v1 = a[1] + bb.y, v2 = a[2] + bb.z, v3 = a[3] + bb.w;
        if (kind == 0) { v0 *= FA_SCALE; v1 *= FA_SCALE; v2 *= FA_SCALE; v3 *= FA_SCALE; }
        if (kind == 2) {
          // V stored with per-64 column involution s: 16a+4b+c -> 16b+4a+c
          int sp = (s & ~60) | ((s & 48) >> 2) | ((s & 12) << 2);
          size_t base = ((size_t)(b * H_ + h) * HD_ + hd) * S_ + sp;
          dst[base]          = f2bf(v0);
          dst[base + S_]     = f2bf(v1);
          dst[base + 2 * S_] = f2bf(v2);
          dst[base + 3 * S_] = f2bf(v3);
        } else {
          uint2 pk;
          pk.x = pack_bf2(v0, v1);
          pk.y = pack_bf2(v2, v3);
          *(uint2*)(dst + ((size_t)(b * H_ + h) * S_ + s) * HD_ + hd) = pk;
        }
      }
    }
  } else {
    #pragma unroll
    for (int ni = 0; ni < 4; ++ni) {
      int n = n0 + wx * 64 + ni * 16 + q8 * 4;
      float4 bb = *(const float4*)(b0 + n);
      #pragma unroll
      for (int mi = 0; mi < 4; ++mi) {
        int m = m0 + wy * 64 + mi * 16 + l16;
        size_t idx = (size_t)m * N + n;
        f32x4 a = acc[mi][ni];
        if constexpr (MODE == 2) {
          float4 r4 = *(const float4*)(resF + idx);
          uint2 pk;
          pk.x = pack_bf2(r4.x + a[0] + bb.x, r4.y + a[1] + bb.y);
          pk.y = pack_bf2(r4.z + a[2] + bb.z, r4.w + a[3] + bb.w);
          *(uint2*)(o0 + idx) = pk;
        } else if constexpr (MODE == 4) {
          ushort4 r4 = *(const ushort4*)(resB + idx);
          float4 o4;
          o4.x = bf2f(r4.x) + a[0] + bb.x;
          o4.y = bf2f(r4.y) + a[1] + bb.y;
          o4.z = bf2f(r4.z) + a[2] + bb.z;
          o4.w = bf2f(r4.w) + a[3] + bb.w;
          *(float4*)(outF + idx) = o4;
        } else {  // MODE 3
          uint2 pk;
          pk.x = pack_bf2(fgelu(a[0] + bb.x), fgelu(a[1] + bb.y));
          pk.y = pack_bf2(fgelu(a[2] + bb.z), fgelu(a[3] + bb.w));
          *(uint2*)(o0 + idx) = pk;
        }
      }
    }
  }
}

// ================= GEMM 128x128, BK=64, 4 waves, 2 blocks/CU, A 2-deep =================
// (control: Wo and FFN2, whose grids cap residency at 2/CU anyway)
template <int MODE>
__global__ __launch_bounds__(256, 2) void gemmK(
    const ushort_t* __restrict__ A, const ushort_t* __restrict__ BT,
    const float* __restrict__ b0, const float* __restrict__ b1,
    const float* __restrict__ b2, const float* __restrict__ resF,
    const ushort_t* __restrict__ resB,
    float* __restrict__ outF, ushort_t* __restrict__ o0,
    ushort_t* __restrict__ o1, ushort_t* __restrict__ o2,
    int M, int N, int K) {
  __shared__ __align__(16) ushort_t lsA[3][128 * 64];
  __shared__ __align__(16) ushort_t lsB[2][128 * 64];
  const int t = threadIdx.x;
  const int lane = t & 63, w = t >> 6;          // 4 waves
  const int wy = w >> 1, wx = w & 1;
  const int q8 = lane >> 4, l16 = lane & 15;
  const int c7 = l16 & 7;

  const int nX = gridDim.x;
  const int lin = blockIdx.y * nX + blockIdx.x;
  const int cpx = (nX * gridDim.y) >> 3;   // nwg % 8 == 0 at all call sites
  const int L = (lin & 7) * cpx + (lin >> 3);
  const int n0 = (L % nX) * 128;
  const int m0 = (L / nX) * 128;

  const int srow = lane >> 3;              // 0..7
  const int schk = (lane & 7) ^ srow;      // pre-swizzled global chunk
  const ushort_t* Ab = A  + (size_t)(m0 + w * 8 + srow) * K + schk * 8;
  const ushort_t* Bb = BT + (size_t)(n0 + w * 8 + srow) * K + schk * 8;

  auto stageA = [&](int k0, int buf) {
    #pragma unroll
    for (int i = 0; i < 4; ++i)
      gload16(Ab + (size_t)(i * 32) * K + k0, &lsA[buf][(i * 32 + w * 8) * 64]);
  };
  auto stageB = [&](int k0, int buf) {
    #pragma unroll
    for (int i = 0; i < 4; ++i)
      gload16(Bb + (size_t)(i * 32) * K + k0, &lsB[buf][(i * 32 + w * 8) * 64]);
  };

  auto ldA = [&](int buf, bf16x8 (&A4)[4][2]) {
    #pragma unroll
    for (int mi = 0; mi < 4; ++mi) {
      const ushort_t* p = &lsA[buf][(wy * 64 + mi * 16 + l16) * 64];
      A4[mi][0] = *(const bf16x8*)(p + ((q8 ^ c7) << 3));
      A4[mi][1] = *(const bf16x8*)(p + (((4 + q8) ^ c7) << 3));
    }
  };
  auto ldB = [&](int buf, bf16x8 (&B4)[4][2]) {
    #pragma unroll
    for (int ni = 0; ni < 4; ++ni) {
      const ushort_t* p = &lsB[buf][(wx * 64 + ni * 16 + l16) * 64];
      B4[ni][0] = *(const bf16x8*)(p + ((q8 ^ c7) << 3));
      B4[ni][1] = *(const bf16x8*)(p + (((4 + q8) ^ c7) << 3));
    }
  };

  f32x4 acc[4][4] = {};
  const int nT = K >> 6;   // >= 16 at all call sites
  stageA(0, 0);
  stageB(0, 0);
  stageA(64, 1);

  bf16x8 bA[4][2], bB[4][2];
  int bufA = 0;
  for (int U = 0; U < nT; ++U) {
    const int bufB = U & 1;
    if (U + 1 < nT) stageB((U + 1) << 6, bufB ^ 1);
    if (U + 2 < nT) {
      int bufA2 = bufA + 2; if (bufA2 >= 3) bufA2 -= 3;
      stageA((U + 2) << 6, bufA2);
    }
    if (U + 2 < nT)      asm volatile("s_waitcnt vmcnt(12)" ::: "memory");
    else if (U + 1 < nT) asm volatile("s_waitcnt vmcnt(8)"  ::: "memory");
    else                 asm volatile("s_waitcnt vmcnt(0)"  ::: "memory");
    BARM();
    ldA(bufA, bA);
    ldB(bufB, bB);
    LGKM0();
    __builtin_amdgcn_s_setprio(1);
    #pragma unroll
    for (int mi = 0; mi < 4; ++mi)
      #pragma unroll
      for (int ni = 0; ni < 4; ++ni) {
        f32x4 c = acc[mi][ni];
        c = __builtin_amdgcn_mfma_f32_16x16x32_bf16(bB[ni][0], bA[mi][0], c, 0, 0, 0);
        c = __builtin_amdgcn_mfma_f32_16x16x32_bf16(bB[ni][1], bA[mi][1], c, 0, 0, 0);
        acc[mi][ni] = c;
      }
    __builtin_amdgcn_s_setprio(0);
    BARM();
    bufA = (bufA == 2) ? 0 : bufA + 1;
  }

  // ---- epilogues: acc[mi][ni]; m = m0+wy*64+mi*16+l16, n = n0+wx*64+ni*16+q8*4
  if constexpr (MODE == 5) {
    const int kind = n0 >> 10;
    const float* bp = (kind == 0) ? b0 : (kind == 1) ? b1 : b2;
    ushort_t* dst = (kind == 0) ? o0 : (kind == 1) ? o1 : o2;
    #pragma unroll
    for (int ni = 0; ni < 4; ++ni) {
      int nn = (n0 & 1023) + wx * 64 + ni * 16 + q8 * 4;
      int h = nn >> 6, hd = nn & 63;
      float4 bb = *(const float4*)(bp + nn);
      #pragma unroll
      for (int mi = 0; mi < 4; ++mi) {
        int m = m0 + wy * 64 + mi * 16 + l16;
        int b = m >> 11, s = m & (S_ - 1);
        f32x4 a = acc[mi][ni];
        float v0 = a[0] + bb.x, v1 = a[1] + bb.y, v2 = a[2] + bb.z, v3 = a[3] + bb.w;
        if (kind == 0) { v0 *= FA_SCALE; v1 *= FA_SCALE; v2 *= FA_SCALE; v3 *= FA_SCALE; }
        if (kind == 2) {
          int sp = (s & ~60) | ((s & 48) >> 2) | ((s & 12) << 2);
          size_t base = ((size_t)(b * H_ + h) * HD_ + hd) * S_ + sp;
          dst[base]          = f2bf(v0);
          dst[base + S_]     = f2bf(v1);
          dst[base + 2 * S_] = f2bf(v2);
          dst[base + 3 * S_] = f2bf(v3);
        } else {
          uint2 pk;
          pk.x = pack_bf2(v0, v1);
          pk.y = pack_bf2(v2, v3);
          *(uint2*)(dst + ((size_t)(b * H_ + h) * S_ + s) * HD_ + hd) = pk;
        }
      }
    }
  } else {
    #pragma unroll
    for (int ni = 0; ni < 4; ++ni) {
      int n = n0 + wx * 64 + ni * 16 + q8 * 4;
      float4 bb = *(const float4*)(b0 + n);
      #pragma unroll
      for (int mi = 0; mi < 4; ++mi) {
        int m = m0 + wy * 64 + mi * 16 + l16;
        size_t idx = (size_t)m * N + n;
        f32x4 a = acc[mi][ni];
        if constexpr (MODE == 2) {
          float4 r4 = *(const float4*)(resF + idx);
          uint2 pk;
          pk.x = pack_bf2(r4.x + a[0] + bb.x, r4.y + a[1] + bb.y);
          pk.y = pack_bf2(r4.z + a[2] + bb.z, r4.w + a[3] + bb.w);
          *(uint2*)(o0 + idx) = pk;
        } else if constexpr (MODE == 4) {
          ushort4 r4 = *(const ushort4*)(resB + idx);
          float4 o4;
          o4.x = bf2f(r4.x) + a[0] + bb.x;
          o4.y = bf2f(r4.y) + a[1] + bb.y;
          o4.z = bf2f(r4.z) + a[2] + bb.z;
          o4.w = bf2f(r4.w) + a[3] + bb.w;
          *(float4*)(outF + idx) = o4;
        } else {  // MODE 3
          uint2 pk;
          pk.x = pack_bf2(fgelu(a[0] + bb.x), fgelu(a[1] + bb.y));
          pk.y = pack_bf2(fgelu(a[2] + bb.z), fgelu(a[3] + bb.w));
          *(uint2*)(o0 + idx) = pk;
        }
      }
    }
  }
}

// ---------------- flash attention v6 (register-resident P, 32 KB LDS, 4 blocks/CU) ----
__global__ __launch_bounds__(256, 4) void flash_attn(
    const ushort_t* __restrict__ Qt, const ushort_t* __restrict__ Kt,
    const ushort_t* __restrict__ Vt, ushort_t* __restrict__ Ao) {
  __shared__ __align__(16) ushort_t ks[2][64 * 64];
  __shared__ __align__(16) ushort_t vs[2][64 * 64];
  const int t = threadIdx.x;
  const int lane = t & 63, w = t >> 6;
  const int q8 = lane >> 4, l16 = lane & 15;
  const int bh = blockIdx.x, q0 = blockIdx.y * 128;
  const int c7 = l16 & 7;
  const int koff0 = ((q8)     ^ c7) * 8;
  const int koff1 = ((4 + q8) ^ c7) * 8;
  const int voff0 = ((2 * q8)     ^ c7) * 8;
  const int voff1 = ((2 * q8 + 1) ^ c7) * 8;

  bf16x8 bq[2][2];
  #pragma unroll
  for (int u = 0; u < 2; ++u)
    #pragma unroll
    for (int kc = 0; kc < 2; ++kc) {
      int row = q0 + w * 32 + u * 16 + l16;
      bq[u][kc] = *(const bf16x8*)(Qt + ((size_t)bh * S_ + row) * HD_ + kc * 32 + q8 * 8);
    }

  const int srow8 = t >> 3;
  const int sgch = (t & 7) ^ (srow8 & 7);
  const ushort_t* Kp = Kt + (size_t)bh * S_ * HD_ + srow8 * HD_ + sgch * 8;
  const ushort_t* Vp = Vt + (size_t)bh * HD_ * S_ + (size_t)srow8 * S_ + sgch * 8;
  const int ldsoff = w * 512;

  #pragma unroll
  for (int i = 0; i < 2; ++i) {
    gload16(Kp + (size_t)(i * 32) * HD_, ks[0] + i * 2048 + ldsoff);
    gload16(Vp + (size_t)(i * 32) * S_,  vs[0] + i * 2048 + ldsoff);
  }

  bf16x8 kone;
  #pragma unroll
  for (int i = 0; i < 8; ++i) kone[i] = (__bf16)1.0f;

  f32x4 accO[2][4] = {};
  f32x4 accL[2] = {};

  for (int it = 0; it < S_ / 64; ++it) {
    __syncthreads();
    const int cur = it & 1;
    if (it + 1 < S_ / 64) {
      const ushort_t* Kn = Kp + (size_t)(it + 1) * 64 * HD_;
      const ushort_t* Vn = Vp + (it + 1) * 64;
      #pragma unroll
      for (int i = 0; i < 2; ++i) {
        gload16(Kn + (size_t)(i * 32) * HD_, ks[cur ^ 1] + i * 2048 + ldsoff);
        gload16(Vn + (size_t)(i * 32) * S_,  vs[cur ^ 1] + i * 2048 + ldsoff);
      }
    }
    const ushort_t* kbuf = ks[cur];
    const ushort_t* vbuf = vs[cur];

    // ---- S^T = K . Q^T ----
    f32x4 st[2][4];
    #pragma unroll
    for (int ni = 0; ni < 4; ++ni) {
      const ushort_t* kr = kbuf + (ni * 16 + l16) * 64;
      bf16x8 ak0 = *(const bf16x8*)(kr + koff0);
      bf16x8 ak1 = *(const bf16x8*)(kr + koff1);
      #pragma unroll
      for (int u = 0; u < 2; ++u) {
        f32x4 z = {0.f, 0.f, 0.f, 0.f};
        z = __builtin_amdgcn_mfma_f32_16x16x32_bf16(ak0, bq[u][0], z, 0, 0, 0);
        z = __builtin_amdgcn_mfma_f32_16x16x32_bf16(ak1, bq[u][1], z, 0, 0, 0);
        st[u][ni] = z;
      }
    }
    // ---- exp2 + pack (round-half-up pack_bf2) ----
    bf16x8 bp[2][2];
    #pragma unroll
    for (int u = 0; u < 2; ++u) {
      uint2 pk[4];
      #pragma unroll
      for (int ni = 0; ni < 4; ++ni) {
        pk[ni].x = pack_bf2(fexp2(st[u][ni][0]), fexp2(st[u][ni][1]));
        pk[ni].y = pack_bf2(fexp2(st[u][ni][2]), fexp2(st[u][ni][3]));
      }
      u32x4 d0 = {pk[0].x, pk[0].y, pk[1].x, pk[1].y};
      u32x4 d1 = {pk[2].x, pk[2].y, pk[3].x, pk[3].y};
      bp[u][0] = __builtin_bit_cast(bf16x8, d0);
      bp[u][1] = __builtin_bit_cast(bf16x8, d1);
    }
    // ---- denominator on MFMA pipe ----
    #pragma unroll
    for (int u = 0; u < 2; ++u) {
      accL[u] = __builtin_amdgcn_mfma_f32_16x16x32_bf16(kone, bp[u][0], accL[u], 0, 0, 0);
      accL[u] = __builtin_amdgcn_mfma_f32_16x16x32_bf16(kone, bp[u][1], accL[u], 0, 0, 0);
    }
    // ---- O^T += V^T . P^T ----
    #pragma unroll
    for (int ni = 0; ni < 4; ++ni) {
      const ushort_t* vr = vbuf + (ni * 16 + l16) * 64;
      bf16x8 av0 = *(const bf16x8*)(vr + voff0);
      bf16x8 av1 = *(const bf16x8*)(vr + voff1);
      #pragma unroll
      for (int u = 0; u < 2; ++u) {
        accO[u][ni] = __builtin_amdgcn_mfma_f32_16x16x32_bf16(av0, bp[u][0], accO[u][ni], 0, 0, 0);
        accO[u][ni] = __builtin_amdgcn_mfma_f32_16x16x32_bf16(av1, bp[u][1], accO[u][ni], 0, 0, 0);
      }
    }
  }

  const int b = bh >> 4, h = bh & 15;
  #pragma unroll
  for (int u = 0; u < 2; ++u) {
    float inv = 1.0f / accL[u][0];
    int q = q0 + w * 32 + u * 16 + l16;
    #pragma unroll
    for (int ni = 0; ni < 4; ++ni) {
      uint2 pk;
      pk.x = pack_bf2(accO[u][ni][0] * inv, accO[u][ni][1] * inv);
      pk.y = pack_bf2(accO[u][ni][2] * inv, accO[u][ni][3] * inv);
      *(uint2*)(Ao + (((size_t)b * S_ + q) * H_ + h) * HD_ + ni * 16 + q8 * 4) = pk;
    }
  }
}

extern "C" void kernel_launch(void* const* d_in, const int* in_sizes, int n_in,
                              void* d_out, int out_size, void* d_ws, size_t ws_size,
                              hipStream_t stream) {
  const float* x    = (const float*)d_in[0];
  const float* Wq   = (const float*)d_in[1];
  const float* bq   = (const float*)d_in[2];
  const float* Wk   = (const float*)d_in[3];
  const float* bk   = (const float*)d_in[4];
  const float* Wv   = (const float*)d_in[5];
  const float* bv   = (const float*)d_in[6];
  const float* Wo   = (const float*)d_in[7];
  const float* bo   = (const float*)d_in[8];
  const float* ln1g = (const float*)d_in[9];
  const float* ln1b = (const float*)d_in[10];
  const float* ln2g = (const float*)d_in[11];
  const float* ln2b = (const float*)d_in[12];
  const float* W1   = (const float*)d_in[13];
  const float* b1   = (const float*)d_in[14];
  const float* W2   = (const float*)d_in[15];
  const float* b2   = (const float*)d_in[16];
  float* out = (float*)d_out;

  char* ws = (char*)d_ws;
  ushort_t* WqT = (ushort_t*)(ws + (size_t)(0)  * (1 << 20));  // 2 MB  } contiguous
  ushort_t* WkT = (ushort_t*)(ws + (size_t)(2)  * (1 << 20));  // 2 MB  } [3072][1024]
  ushort_t* WvT = (ushort_t*)(ws + (size_t)(4)  * (1 << 20));  // 2 MB  } fused QKV
  ushort_t* WoT = (ushort_t*)(ws + (size_t)(6)  * (1 << 20));  // 2 MB
  ushort_t* W1T = (ushort_t*)(ws + (size_t)(8)  * (1 << 20));  // 8 MB  [DF][D]
  ushort_t* W2T = (ushort_t*)(ws + (size_t)(16) * (1 << 20));  // 8 MB  [D][DF]
  ushort_t* xn  = (ushort_t*)(ws + (size_t)(24) * (1 << 20));  // 16 MB [M][D]
  ushort_t* qT  = (ushort_t*)(ws + (size_t)(40) * (1 << 20));  // 16 MB [BH][S][HD]
  ushort_t* kT  = (ushort_t*)(ws + (size_t)(56) * (1 << 20));  // 16 MB
  ushort_t* vT  = (ushort_t*)(ws + (size_t)(72) * (1 << 20));  // 16 MB [BH][HD][S-perm]
  ushort_t* ao  = (ushort_t*)(ws + (size_t)(88) * (1 << 20));  // 16 MB [B,S,H,HD]
  ushort_t* x2b = (ushort_t*)(ws + (size_t)(104)* (1 << 20));  // 16 MB [M][D] bf16 residual
  ushort_t* hb  = (ushort_t*)(ws + (size_t)(136)* (1 << 20));  // 64 MB [M][DF]

  dim3 blk(256);

  // fused transposes (64x64 tiles) + LN1
  PrepArgs pa;
  pa.w4src[0] = Wq; pa.w4src[1] = Wk; pa.w4src[2] = Wv; pa.w4src[3] = Wo;
  pa.w4dst[0] = WqT; pa.w4dst[1] = WkT; pa.w4dst[2] = WvT; pa.w4dst[3] = WoT;
  pa.W1 = W1; pa.W1T = W1T; pa.W2 = W2; pa.W2T = W2T;
  pa.x = x; pa.g = ln1g; pa.b = ln1b; pa.xn = xn;
  prep_kernel<<<3072 + M_, blk, 0, stream>>>(pa);

  // fused QKV projection: 24x64 = 1536 blocks, 32KB LDS -> 4-5 blocks/CU
  gemmK32<5><<<dim3(3072/128, M_/128), blk, 0, stream>>>(
      xn, WqT, bq, bk, bv, nullptr, nullptr, nullptr, qT, kT, vT, M_, 3072, D_);
  // attention: 1024 blocks, 4 blocks/CU
  flash_attn<<<dim3(B_*H_, S_/128), blk, 0, stream>>>(qT, kT, vT, ao);
  // output projection + residual -> bf16 x2: 8x64 = 512 blocks (control, gemmK)
  gemmK<2><<<dim3(D_/128, M_/128), blk, 0, stream>>>(
      ao, WoT, bo, nullptr, nullptr, x, nullptr, nullptr, x2b, nullptr, nullptr, M_, D_, D_);
  // LN2 (bf16 in)
  ln_kernel<1><<<M_, blk, 0, stream>>>(x2b, ln2g, ln2b, xn);
  // FFN1: 32x64 = 2048 blocks, 32KB LDS -> 4-5 blocks/CU (experiment arm)
  gemmK32<3><<<dim3(DF_/128, M_/128), blk, 0, stream>>>(
      xn, W1T, b1, nullptr, nullptr, nullptr, nullptr, nullptr, hb, nullptr, nullptr, M_, DF_, D_);
  // FFN2: 8x64 = 512 blocks, K=4096 (control, gemmK)
  gemmK<4><<<dim3(D_/128, M_/128), blk, 0, stream>>>(
      hb, W2T, b2, nullptr, nullptr, nullptr, x2b, out, nullptr, nullptr, nullptr, M_, D_, DF_);
}

// Round 9
// 458.699 us; speedup vs baseline: 1.0991x; 1.0991x over previous
//
#include <hip/hip_runtime.h>
#include <math.h>

#define B_  4
#define S_  2048
#define D_  1024
#define H_  16
#define HD_ 64
#define DF_ 4096
#define M_  (B_*S_)   // 8192 rows

typedef unsigned short ushort_t;
typedef __bf16 bf16x8 __attribute__((ext_vector_type(8)));
typedef float  f32x4  __attribute__((ext_vector_type(4)));
typedef unsigned u32x4 __attribute__((ext_vector_type(4)));

#define FA_SCALE 0.18033688011112042f  // (1/8) * log2(e)

__device__ __forceinline__ ushort_t f2bf(float f) {
  union { float f; unsigned u; } v; v.f = f;
  unsigned r = v.u + 0x7FFFu + ((v.u >> 16) & 1u);
  return (ushort_t)(r >> 16);
}

__device__ __forceinline__ float bf2f(ushort_t u) {
  union { unsigned u; float f; } v; v.u = ((unsigned)u) << 16; return v.f;
}

// round-half-up bf16 pack of two floats -> u32 (lo = a, hi = b), 3 VALU ops
__device__ __forceinline__ unsigned pack_bf2(float a, float b) {
  union { float f; unsigned u; } ua, ub; ua.f = a; ub.f = b;
  return __builtin_amdgcn_perm(ub.u + 0x8000u, ua.u + 0x8000u, 0x07060302u);
}

__device__ __forceinline__ float fexp2(float x) {
#if __has_builtin(__builtin_amdgcn_exp2f)
  return __builtin_amdgcn_exp2f(x);
#else
  return __expf(x * 0.6931471805599453f);
#endif
}

// tanh-form GELU via exp2+rcp: ~5 VALU ops
__device__ __forceinline__ float fgelu(float x) {
  float e = fexp2(x * fmaf(x * x, -0.10295358f, -2.30221510f));
  return x * __builtin_amdgcn_rcpf(1.0f + e);
}

__device__ __forceinline__ void gload16(const void* g, void* l) {
  __builtin_amdgcn_global_load_lds(
      (const __attribute__((address_space(1))) void*)g,
      (__attribute__((address_space(3))) void*)l, 16, 0, 0);
}

// raw barrier with compiler memory fence (no vmcnt drain)
#define BARM() do { asm volatile("" ::: "memory"); \
                    __builtin_amdgcn_s_barrier();  \
                    asm volatile("" ::: "memory"); } while (0)
#define LGKM0() asm volatile("s_waitcnt lgkmcnt(0)" ::: "memory")

// ======== fused prep: 6 weight transposes (fp32->bf16^T, 64x64 tiles) + LN1 ========
struct PrepArgs {
  const float* w4src[4]; ushort_t* w4dst[4];
  const float* W1; ushort_t* W1T;
  const float* W2; ushort_t* W2T;
  const float* x; const float* g; const float* b; ushort_t* xn;
};

__global__ __launch_bounds__(256) void prep_kernel(PrepArgs p) {
  __shared__ float tile[64][65];
  __shared__ float sh[8];
  const int bid = blockIdx.x;
  const int t = threadIdx.x;
  if (bid < 3072) {
    const float* in; ushort_t* out; int R, C, bx, by;
    if (bid < 1024) {
      int j = bid >> 8, tt = bid & 255;
      in = p.w4src[j]; out = p.w4dst[j]; R = D_; C = D_; bx = tt & 15; by = tt >> 4;
    } else if (bid < 2048) {
      int tt = bid - 1024;
      in = p.W1; out = p.W1T; R = D_; C = DF_; bx = tt & 63; by = tt >> 6;
    } else {
      int tt = bid - 2048;
      in = p.W2; out = p.W2T; R = DF_; C = D_; bx = tt & 15; by = tt >> 4;
    }
    int r0 = by * 64, c0 = bx * 64;
    int lcol = t & 63, lrow = t >> 6;
    #pragma unroll
    for (int i = 0; i < 16; ++i)
      tile[lrow + 4 * i][lcol] = in[(size_t)(r0 + lrow + 4 * i) * C + c0 + lcol];
    __syncthreads();
    int l32 = t & 31, hw = t >> 5;
    #pragma unroll
    for (int i = 0; i < 8; ++i) {
      int c = hw + 8 * i;
      unsigned v = pack_bf2(tile[2 * l32][c], tile[2 * l32 + 1][c]);
      *(unsigned*)(out + (size_t)(c0 + c) * R + r0 + 2 * l32) = v;
    }
  } else {
    // LN1 row (fp32 in -> bf16 out)
    int row = bid - 3072;
    float4 v = ((const float4*)(p.x + (size_t)row * D_))[t];
    float s  = v.x + v.y + v.z + v.w;
    float ss = v.x*v.x + v.y*v.y + v.z*v.z + v.w*v.w;
    #pragma unroll
    for (int off = 32; off > 0; off >>= 1) {
      s  += __shfl_down(s, off);
      ss += __shfl_down(ss, off);
    }
    int w = t >> 6, lane = t & 63;
    if (lane == 0) { sh[w] = s; sh[4 + w] = ss; }
    __syncthreads();
    if (t == 0) {
      float a  = sh[0] + sh[1] + sh[2] + sh[3];
      float a2 = sh[4] + sh[5] + sh[6] + sh[7];
      float mean = a * (1.0f / D_);
      float var  = a2 * (1.0f / D_) - mean * mean;
      sh[0] = mean; sh[1] = rsqrtf(var + 1e-5f);
    }
    __syncthreads();
    float mean = sh[0], rstd = sh[1];
    float4 gv = ((const float4*)p.g)[t];
    float4 bv = ((const float4*)p.b)[t];
    ushort4 o;
    o.x = f2bf((v.x - mean) * rstd * gv.x + bv.x);
    o.y = f2bf((v.y - mean) * rstd * gv.y + bv.y);
    o.z = f2bf((v.z - mean) * rstd * gv.z + bv.z);
    o.w = f2bf((v.w - mean) * rstd * gv.w + bv.w);
    ((ushort4*)(p.xn + (size_t)row * D_))[t] = o;
  }
}

// ---------------- layernorm row(1024) -> bf16 (bf16 input) ----------------
template <int BF_IN>
__global__ __launch_bounds__(256) void ln_kernel(
    const void* __restrict__ xv, const float* __restrict__ g,
    const float* __restrict__ b, ushort_t* __restrict__ out) {
  int row = blockIdx.x;
  int t = threadIdx.x;
  float4 v;
  if constexpr (BF_IN) {
    ushort4 raw = ((const ushort4*)((const ushort_t*)xv + (size_t)row * D_))[t];
    v.x = bf2f(raw.x); v.y = bf2f(raw.y); v.z = bf2f(raw.z); v.w = bf2f(raw.w);
  } else {
    v = ((const float4*)((const float*)xv + (size_t)row * D_))[t];
  }
  float s  = v.x + v.y + v.z + v.w;
  float ss = v.x*v.x + v.y*v.y + v.z*v.z + v.w*v.w;
  #pragma unroll
  for (int off = 32; off > 0; off >>= 1) {
    s  += __shfl_down(s, off);
    ss += __shfl_down(ss, off);
  }
  __shared__ float sh[8];
  int w = t >> 6, lane = t & 63;
  if (lane == 0) { sh[w] = s; sh[4 + w] = ss; }
  __syncthreads();
  if (t == 0) {
    float a  = sh[0] + sh[1] + sh[2] + sh[3];
    float a2 = sh[4] + sh[5] + sh[6] + sh[7];
    float mean = a * (1.0f / D_);
    float var  = a2 * (1.0f / D_) - mean * mean;
    sh[0] = mean; sh[1] = rsqrtf(var + 1e-5f);
  }
  __syncthreads();
  float mean = sh[0], rstd = sh[1];
  float4 gv = ((const float4*)g)[t];
  float4 bv = ((const float4*)b)[t];
  ushort4 o;
  o.x = f2bf((v.x - mean) * rstd * gv.x + bv.x);
  o.y = f2bf((v.y - mean) * rstd * gv.y + bv.y);
  o.z = f2bf((v.z - mean) * rstd * gv.z + bv.z);
  o.w = f2bf((v.w - mean) * rstd * gv.w + bv.w);
  ((ushort4*)(out + (size_t)row * D_))[t] = o;
}

// ================= GEMM 256x256, BK=64, 8 waves, m201-style 4-phase =================
// (FFN1: 1 block/CU, deep phase pipeline -- R7 best for this shape)
template <int MODE>
__global__ __launch_bounds__(512, 2) void gemm256(
    const ushort_t* __restrict__ A, const ushort_t* __restrict__ BT,
    const float* __restrict__ b0, const float* __restrict__ b1,
    const float* __restrict__ b2, const float* __restrict__ resF,
    const ushort_t* __restrict__ resB,
    float* __restrict__ outF, ushort_t* __restrict__ o0,
    ushort_t* __restrict__ o1, ushort_t* __restrict__ o2,
    int M, int N, int K) {
  __shared__ __align__(16) ushort_t lsA[2][2][128 * 64];  // [buf][half][row*64]
  __shared__ __align__(16) ushort_t lsB[2][2][128 * 64];
  const int t = threadIdx.x;
  const int lane = t & 63, w = t >> 6;
  const int wy = w >> 2, wx = w & 3;
  const int q8 = lane >> 4, l16 = lane & 15;
  const int c7 = l16 & 7;

  const int nX = gridDim.x;
  const int lin = blockIdx.y * nX + blockIdx.x;
  const int cpx = (nX * gridDim.y) >> 3;
  const int L = (lin & 7) * cpx + (lin >> 3);
  const int n0 = (L % nX) * 256;
  const int m0 = (L / nX) * 256;

  const int srow = lane >> 3;
  const int schk = (lane & 7) ^ srow;
  const ushort_t* Ab = A  + (size_t)(m0 + w * 8 + srow) * K + schk * 8;
  const ushort_t* Bb = BT + (size_t)(n0 + w * 8 + srow) * K + schk * 8;

  auto stageA = [&](int k0, int buf, int half) {
    #pragma unroll
    for (int i = 0; i < 2; ++i)
      gload16(Ab + (size_t)((half * 2 + i) * 64) * K + k0,
              &lsA[buf][half][(i * 64 + w * 8) * 64]);
  };
  auto stageB = [&](int k0, int buf, int half) {
    #pragma unroll
    for (int i = 0; i < 2; ++i)
      gload16(Bb + (size_t)((half * 2 + i) * 64) * K + k0,
              &lsB[buf][half][(i * 64 + w * 8) * 64]);
  };

  auto ldA = [&](int buf, int mh, bf16x8 (&A4)[4][2]) {
    #pragma unroll
    for (int mi = 0; mi < 4; ++mi) {
      const ushort_t* p = &lsA[buf][mh][(wy * 64 + mi * 16 + l16) * 64];
      A4[mi][0] = *(const bf16x8*)(p + ((q8 ^ c7) << 3));
      A4[mi][1] = *(const bf16x8*)(p + (((4 + q8) ^ c7) << 3));
    }
  };
  auto ldB = [&](int buf, int nh, bf16x8 (&B2)[2][2]) {
    #pragma unroll
    for (int ni = 0; ni < 2; ++ni) {
      const ushort_t* p = &lsB[buf][nh][(wx * 32 + ni * 16 + l16) * 64];
      B2[ni][0] = *(const bf16x8*)(p + ((q8 ^ c7) << 3));
      B2[ni][1] = *(const bf16x8*)(p + (((4 + q8) ^ c7) << 3));
    }
  };

  f32x4 acc[8][4] = {};
  auto mfmaQ = [&](int mh, int nh, bf16x8 (&A4)[4][2], bf16x8 (&B2)[2][2]) {
    #pragma unroll
    for (int mi = 0; mi < 4; ++mi)
      #pragma unroll
      for (int ni = 0; ni < 2; ++ni) {
        f32x4 c = acc[mh * 4 + mi][nh * 2 + ni];
        c = __builtin_amdgcn_mfma_f32_16x16x32_bf16(B2[ni][0], A4[mi][0], c, 0, 0, 0);
        c = __builtin_amdgcn_mfma_f32_16x16x32_bf16(B2[ni][1], A4[mi][1], c, 0, 0, 0);
        acc[mh * 4 + mi][nh * 2 + ni] = c;
      }
  };

  const int nT = K >> 6;
  stageA(0, 0, 0); stageB(0, 0, 0); stageA(0, 0, 1); stageB(0, 0, 1);
  stageA(64, 1, 0); stageB(64, 1, 0); stageA(64, 1, 1);

  bf16x8 bA[4][2];
  bf16x8 bB[2][2][2];

  for (int U = 0; U < nT; ++U) {
    const int buf = U & 1;
    if (U == nT - 1) asm volatile("s_waitcnt vmcnt(0)" ::: "memory");
    else             asm volatile("s_waitcnt vmcnt(6)" ::: "memory");
    BARM();
    // P1
    ldA(buf, 0, bA);
    ldB(buf, 0, bB[0]);
    if (U + 1 < nT) stageB((U + 1) << 6, buf ^ 1, 1);
    BARM(); LGKM0();
    __builtin_amdgcn_s_setprio(1); mfmaQ(0, 0, bA, bB[0]); __builtin_amdgcn_s_setprio(0);
    BARM();
    // P2
    ldB(buf, 1, bB[1]);
    if (U + 2 < nT) stageA((U + 2) << 6, buf, 0);
    BARM(); LGKM0();
    __builtin_amdgcn_s_setprio(1); mfmaQ(0, 1, bA, bB[1]); __builtin_amdgcn_s_setprio(0);
    BARM();
    // P3
    ldA(buf, 1, bA);
    if (U + 2 < nT) stageB((U + 2) << 6, buf, 0);
    BARM(); LGKM0();
    __builtin_amdgcn_s_setprio(1); mfmaQ(1, 1, bA, bB[1]); __builtin_amdgcn_s_setprio(0);
    BARM();
    // P4
    if (U + 2 < nT) stageA((U + 2) << 6, buf, 1);
    BARM();
    __builtin_amdgcn_s_setprio(1); mfmaQ(1, 0, bA, bB[0]); __builtin_amdgcn_s_setprio(0);
  }

  {
    #pragma unroll
    for (int niG = 0; niG < 4; ++niG) {
      int n = n0 + (niG >> 1) * 128 + wx * 32 + (niG & 1) * 16 + q8 * 4;
      float4 bb = *(const float4*)(b0 + n);
      #pragma unroll
      for (int miG = 0; miG < 8; ++miG) {
        int m = m0 + (miG >> 2) * 128 + wy * 64 + (miG & 3) * 16 + l16;
        size_t idx = (size_t)m * N + n;
        f32x4 a = acc[miG][niG];
        if constexpr (MODE == 2) {
          float4 r4 = *(const float4*)(resF + idx);
          uint2 pk;
          pk.x = pack_bf2(r4.x + a[0] + bb.x, r4.y + a[1] + bb.y);
          pk.y = pack_bf2(r4.z + a[2] + bb.z, r4.w + a[3] + bb.w);
          *(uint2*)(o0 + idx) = pk;
        } else if constexpr (MODE == 4) {
          ushort4 r4 = *(const ushort4*)(resB + idx);
          float4 o4;
          o4.x = bf2f(r4.x) + a[0] + bb.x;
          o4.y = bf2f(r4.y) + a[1] + bb.y;
          o4.z = bf2f(r4.z) + a[2] + bb.z;
          o4.w = bf2f(r4.w) + a[3] + bb.w;
          *(float4*)(outF + idx) = o4;
        } else {  // MODE 3
          uint2 pk;
          pk.x = pack_bf2(fgelu(a[0] + bb.x), fgelu(a[1] + bb.y));
          pk.y = pack_bf2(fgelu(a[2] + bb.z), fgelu(a[3] + bb.w));
          *(uint2*)(o0 + idx) = pk;
        }
      }
    }
  }
}

// ================= GEMM 128x128, BK=64, 8 WAVES, 64KB LDS, 2 blocks/CU ==========
// (QKV, Wo, FFN2.) Same R5-verified dbuf/vmcnt pipeline as the 4-wave gemmK, but
// 8 waves of 64x32 per-wave tiles -> 16 waves/CU (4/SIMD) at 2 blocks/CU.
// Mechanism: doubled waves/SIMD hide barrier+vmcnt drains via cross-wave MFMA
// overlap (the lever that gave flash -25% in R6->R7). Per-SIMD MFMA work per
// K-tile is unchanged; only latency hiding doubles.
// Per tile U: issue stage(U+1)->buf^1 (4 gloads/wave), vmcnt(4) [0 at last],
// barrier, ds_read (8 A + 4 B b128), lgkmcnt(0), 16 MFMA (setprio), barrier.
template <int MODE>
__global__ __launch_bounds__(512, 4) void gemmK8(
    const ushort_t* __restrict__ A, const ushort_t* __restrict__ BT,
    const float* __restrict__ b0, const float* __restrict__ b1,
    const float* __restrict__ b2, const float* __restrict__ resF,
    const ushort_t* __restrict__ resB,
    float* __restrict__ outF, ushort_t* __restrict__ o0,
    ushort_t* __restrict__ o1, ushort_t* __restrict__ o2,
    int M, int N, int K) {
  __shared__ __align__(16) ushort_t lsA[2][128 * 64];
  __shared__ __align__(16) ushort_t lsB[2][128 * 64];
  const int t = threadIdx.x;
  const int lane = t & 63, w = t >> 6;          // 8 waves
  const int wy = w >> 2, wx = w & 3;            // per-wave tile 64x32
  const int q8 = lane >> 4, l16 = lane & 15;
  const int c7 = l16 & 7;

  const int nX = gridDim.x;
  const int lin = blockIdx.y * nX + blockIdx.x;
  const int cpx = (nX * gridDim.y) >> 3;   // nwg % 8 == 0 at all call sites
  const int L = (lin & 7) * cpx + (lin >> 3);
  const int n0 = (L % nX) * 128;
  const int m0 = (L / nX) * 128;

  const int srow = lane >> 3;              // 0..7
  const int schk = (lane & 7) ^ srow;      // pre-swizzled global chunk
  const ushort_t* Ab = A  + (size_t)(m0 + w * 8 + srow) * K + schk * 8;
  const ushort_t* Bb = BT + (size_t)(n0 + w * 8 + srow) * K + schk * 8;

  // stage one 128x64 tile: 2 issues/wave, rows i*64 + w*8 + srow
  auto stageA = [&](int k0, int buf) {
    #pragma unroll
    for (int i = 0; i < 2; ++i)
      gload16(Ab + (size_t)(i * 64) * K + k0, &lsA[buf][(i * 64 + w * 8) * 64]);
  };
  auto stageB = [&](int k0, int buf) {
    #pragma unroll
    for (int i = 0; i < 2; ++i)
      gload16(Bb + (size_t)(i * 64) * K + k0, &lsB[buf][(i * 64 + w * 8) * 64]);
  };

  auto ldA = [&](int buf, bf16x8 (&A4)[4][2]) {
    #pragma unroll
    for (int mi = 0; mi < 4; ++mi) {
      const ushort_t* p = &lsA[buf][(wy * 64 + mi * 16 + l16) * 64];
      A4[mi][0] = *(const bf16x8*)(p + ((q8 ^ c7) << 3));
      A4[mi][1] = *(const bf16x8*)(p + (((4 + q8) ^ c7) << 3));
    }
  };
  auto ldB = [&](int buf, bf16x8 (&B2)[2][2]) {
    #pragma unroll
    for (int ni = 0; ni < 2; ++ni) {
      const ushort_t* p = &lsB[buf][(wx * 32 + ni * 16 + l16) * 64];
      B2[ni][0] = *(const bf16x8*)(p + ((q8 ^ c7) << 3));
      B2[ni][1] = *(const bf16x8*)(p + (((4 + q8) ^ c7) << 3));
    }
  };

  f32x4 acc[4][2] = {};
  const int nT = K >> 6;   // >= 16 at all call sites
  stageA(0, 0); stageB(0, 0);

  bf16x8 bA[4][2], bB[2][2];
  for (int U = 0; U < nT; ++U) {
    const int buf = U & 1;
    if (U + 1 < nT) {
      stageA((U + 1) << 6, buf ^ 1);
      stageB((U + 1) << 6, buf ^ 1);
      asm volatile("s_waitcnt vmcnt(4)" ::: "memory");
    } else {
      asm volatile("s_waitcnt vmcnt(0)" ::: "memory");
    }
    BARM();
    ldA(buf, bA);
    ldB(buf, bB);
    LGKM0();
    __builtin_amdgcn_s_setprio(1);
    #pragma unroll
    for (int mi = 0; mi < 4; ++mi)
      #pragma unroll
      for (int ni = 0; ni < 2; ++ni) {
        f32x4 c = acc[mi][ni];
        c = __builtin_amdgcn_mfma_f32_16x16x32_bf16(bB[ni][0], bA[mi][0], c, 0, 0, 0);
        c = __builtin_amdgcn_mfma_f32_16x16x32_bf16(bB[ni][1], bA[mi][1], c, 0, 0, 0);
        acc[mi][ni] = c;
      }
    __builtin_amdgcn_s_setprio(0);
    BARM();
  }

  // ---- epilogues: acc[mi][ni]; m = m0+wy*64+mi*16+l16, n = n0+wx*32+ni*16+q8*4
  if constexpr (MODE == 5) {
    const int kind = n0 >> 10;
    const float* bp = (kind == 0) ? b0 : (kind == 1) ? b1 : b2;
    ushort_t* dst = (kind == 0) ? o0 : (kind == 1) ? o1 : o2;
    #pragma unroll
    for (int ni = 0; ni < 2; ++ni) {
      int nn = (n0 & 1023) + wx * 32 + ni * 16 + q8 * 4;
      int h = nn >> 6, hd = nn & 63;
      float4 bb = *(const float4*)(bp + nn);
      #pragma unroll
      for (int mi = 0; mi < 4; ++mi) {
        int m = m0 + wy * 64 + mi * 16 + l16;
        int b = m >> 11, s = m & (S_ - 1);
        f32x4 a = acc[mi][ni];
        float v0 = a[0] + bb.x, v1 = a[1] + bb.y, v2 = a[2] + bb.z, v3 = a[3] + bb.w;
        if (kind == 0) { v0 *= FA_SCALE; v1 *= FA_SCALE; v2 *= FA_SCALE; v3 *= FA_SCALE; }
        if (kind == 2) {
          // V stored with per-64 column involution s: 16a+4b+c -> 16b+4a+c
          int sp = (s & ~60) | ((s & 48) >> 2) | ((s & 12) << 2);
          size_t base = ((size_t)(b * H_ + h) * HD_ + hd) * S_ + sp;
          dst[base]          = f2bf(v0);
          dst[base + S_]     = f2bf(v1);
          dst[base + 2 * S_] = f2bf(v2);
          dst[base + 3 * S_] = f2bf(v3);
        } else {
          uint2 pk;
          pk.x = pack_bf2(v0, v1);
          pk.y = pack_bf2(v2, v3);
          *(uint2*)(dst + ((size_t)(b * H_ + h) * S_ + s) * HD_ + hd) = pk;
        }
      }
    }
  } else {
    #pragma unroll
    for (int ni = 0; ni < 2; ++ni) {
      int n = n0 + wx * 32 + ni * 16 + q8 * 4;
      float4 bb = *(const float4*)(b0 + n);
      #pragma unroll
      for (int mi = 0; mi < 4; ++mi) {
        int m = m0 + wy * 64 + mi * 16 + l16;
        size_t idx = (size_t)m * N + n;
        f32x4 a = acc[mi][ni];
        if constexpr (MODE == 2) {
          float4 r4 = *(const float4*)(resF + idx);
          uint2 pk;
          pk.x = pack_bf2(r4.x + a[0] + bb.x, r4.y + a[1] + bb.y);
          pk.y = pack_bf2(r4.z + a[2] + bb.z, r4.w + a[3] + bb.w);
          *(uint2*)(o0 + idx) = pk;
        } else if constexpr (MODE == 4) {
          ushort4 r4 = *(const ushort4*)(resB + idx);
          float4 o4;
          o4.x = bf2f(r4.x) + a[0] + bb.x;
          o4.y = bf2f(r4.y) + a[1] + bb.y;
          o4.z = bf2f(r4.z) + a[2] + bb.z;
          o4.w = bf2f(r4.w) + a[3] + bb.w;
          *(float4*)(outF + idx) = o4;
        } else {  // MODE 3
          uint2 pk;
          pk.x = pack_bf2(fgelu(a[0] + bb.x), fgelu(a[1] + bb.y));
          pk.y = pack_bf2(fgelu(a[2] + bb.z), fgelu(a[3] + bb.w));
          *(uint2*)(o0 + idx) = pk;
        }
      }
    }
  }
}

// ---------------- flash attention v6 (register-resident P, 32 KB LDS, 4 blocks/CU) ----
__global__ __launch_bounds__(256, 4) void flash_attn(
    const ushort_t* __restrict__ Qt, const ushort_t* __restrict__ Kt,
    const ushort_t* __restrict__ Vt, ushort_t* __restrict__ Ao) {
  __shared__ __align__(16) ushort_t ks[2][64 * 64];
  __shared__ __align__(16) ushort_t vs[2][64 * 64];
  const int t = threadIdx.x;
  const int lane = t & 63, w = t >> 6;
  const int q8 = lane >> 4, l16 = lane & 15;
  const int bh = blockIdx.x, q0 = blockIdx.y * 128;
  const int c7 = l16 & 7;
  const int koff0 = ((q8)     ^ c7) * 8;
  const int koff1 = ((4 + q8) ^ c7) * 8;
  const int voff0 = ((2 * q8)     ^ c7) * 8;
  const int voff1 = ((2 * q8 + 1) ^ c7) * 8;

  bf16x8 bq[2][2];
  #pragma unroll
  for (int u = 0; u < 2; ++u)
    #pragma unroll
    for (int kc = 0; kc < 2; ++kc) {
      int row = q0 + w * 32 + u * 16 + l16;
      bq[u][kc] = *(const bf16x8*)(Qt + ((size_t)bh * S_ + row) * HD_ + kc * 32 + q8 * 8);
    }

  const int srow8 = t >> 3;
  const int sgch = (t & 7) ^ (srow8 & 7);
  const ushort_t* Kp = Kt + (size_t)bh * S_ * HD_ + srow8 * HD_ + sgch * 8;
  const ushort_t* Vp = Vt + (size_t)bh * HD_ * S_ + (size_t)srow8 * S_ + sgch * 8;
  const int ldsoff = w * 512;

  #pragma unroll
  for (int i = 0; i < 2; ++i) {
    gload16(Kp + (size_t)(i * 32) * HD_, ks[0] + i * 2048 + ldsoff);
    gload16(Vp + (size_t)(i * 32) * S_,  vs[0] + i * 2048 + ldsoff);
  }

  bf16x8 kone;
  #pragma unroll
  for (int i = 0; i < 8; ++i) kone[i] = (__bf16)1.0f;

  f32x4 accO[2][4] = {};
  f32x4 accL[2] = {};

  for (int it = 0; it < S_ / 64; ++it) {
    __syncthreads();
    const int cur = it & 1;
    if (it + 1 < S_ / 64) {
      const ushort_t* Kn = Kp + (size_t)(it + 1) * 64 * HD_;
      const ushort_t* Vn = Vp + (it + 1) * 64;
      #pragma unroll
      for (int i = 0; i < 2; ++i) {
        gload16(Kn + (size_t)(i * 32) * HD_, ks[cur ^ 1] + i * 2048 + ldsoff);
        gload16(Vn + (size_t)(i * 32) * S_,  vs[cur ^ 1] + i * 2048 + ldsoff);
      }
    }
    const ushort_t* kbuf = ks[cur];
    const ushort_t* vbuf = vs[cur];

    // ---- S^T = K . Q^T ----
    f32x4 st[2][4];
    #pragma unroll
    for (int ni = 0; ni < 4; ++ni) {
      const ushort_t* kr = kbuf + (ni * 16 + l16) * 64;
      bf16x8 ak0 = *(const bf16x8*)(kr + koff0);
      bf16x8 ak1 = *(const bf16x8*)(kr + koff1);
      #pragma unroll
      for (int u = 0; u < 2; ++u) {
        f32x4 z = {0.f, 0.f, 0.f, 0.f};
        z = __builtin_amdgcn_mfma_f32_16x16x32_bf16(ak0, bq[u][0], z, 0, 0, 0);
        z = __builtin_amdgcn_mfma_f32_16x16x32_bf16(ak1, bq[u][1], z, 0, 0, 0);
        st[u][ni] = z;
      }
    }
    // ---- exp2 + pack (round-half-up pack_bf2) ----
    bf16x8 bp[2][2];
    #pragma unroll
    for (int u = 0; u < 2; ++u) {
      uint2 pk[4];
      #pragma unroll
      for (int ni = 0; ni < 4; ++ni) {
        pk[ni].x = pack_bf2(fexp2(st[u][ni][0]), fexp2(st[u][ni][1]));
        pk[ni].y = pack_bf2(fexp2(st[u][ni][2]), fexp2(st[u][ni][3]));
      }
      u32x4 d0 = {pk[0].x, pk[0].y, pk[1].x, pk[1].y};
      u32x4 d1 = {pk[2].x, pk[2].y, pk[3].x, pk[3].y};
      bp[u][0] = __builtin_bit_cast(bf16x8, d0);
      bp[u][1] = __builtin_bit_cast(bf16x8, d1);
    }
    // ---- denominator on MFMA pipe ----
    #pragma unroll
    for (int u = 0; u < 2; ++u) {
      accL[u] = __builtin_amdgcn_mfma_f32_16x16x32_bf16(kone, bp[u][0], accL[u], 0, 0, 0);
      accL[u] = __builtin_amdgcn_mfma_f32_16x16x32_bf16(kone, bp[u][1], accL[u], 0, 0, 0);
    }
    // ---- O^T += V^T . P^T ----
    #pragma unroll
    for (int ni = 0; ni < 4; ++ni) {
      const ushort_t* vr = vbuf + (ni * 16 + l16) * 64;
      bf16x8 av0 = *(const bf16x8*)(vr + voff0);
      bf16x8 av1 = *(const bf16x8*)(vr + voff1);
      #pragma unroll
      for (int u = 0; u < 2; ++u) {
        accO[u][ni] = __builtin_amdgcn_mfma_f32_16x16x32_bf16(av0, bp[u][0], accO[u][ni], 0, 0, 0);
        accO[u][ni] = __builtin_amdgcn_mfma_f32_16x16x32_bf16(av1, bp[u][1], accO[u][ni], 0, 0, 0);
      }
    }
  }

  const int b = bh >> 4, h = bh & 15;
  #pragma unroll
  for (int u = 0; u < 2; ++u) {
    float inv = 1.0f / accL[u][0];
    int q = q0 + w * 32 + u * 16 + l16;
    #pragma unroll
    for (int ni = 0; ni < 4; ++ni) {
      uint2 pk;
      pk.x = pack_bf2(accO[u][ni][0] * inv, accO[u][ni][1] * inv);
      pk.y = pack_bf2(accO[u][ni][2] * inv, accO[u][ni][3] * inv);
      *(uint2*)(Ao + (((size_t)b * S_ + q) * H_ + h) * HD_ + ni * 16 + q8 * 4) = pk;
    }
  }
}

extern "C" void kernel_launch(void* const* d_in, const int* in_sizes, int n_in,
                              void* d_out, int out_size, void* d_ws, size_t ws_size,
                              hipStream_t stream) {
  const float* x    = (const float*)d_in[0];
  const float* Wq   = (const float*)d_in[1];
  const float* bq   = (const float*)d_in[2];
  const float* Wk   = (const float*)d_in[3];
  const float* bk   = (const float*)d_in[4];
  const float* Wv   = (const float*)d_in[5];
  const float* bv   = (const float*)d_in[6];
  const float* Wo   = (const float*)d_in[7];
  const float* bo   = (const float*)d_in[8];
  const float* ln1g = (const float*)d_in[9];
  const float* ln1b = (const float*)d_in[10];
  const float* ln2g = (const float*)d_in[11];
  const float* ln2b = (const float*)d_in[12];
  const float* W1   = (const float*)d_in[13];
  const float* b1   = (const float*)d_in[14];
  const float* W2   = (const float*)d_in[15];
  const float* b2   = (const float*)d_in[16];
  float* out = (float*)d_out;

  char* ws = (char*)d_ws;
  ushort_t* WqT = (ushort_t*)(ws + (size_t)(0)  * (1 << 20));  // 2 MB  } contiguous
  ushort_t* WkT = (ushort_t*)(ws + (size_t)(2)  * (1 << 20));  // 2 MB  } [3072][1024]
  ushort_t* WvT = (ushort_t*)(ws + (size_t)(4)  * (1 << 20));  // 2 MB  } fused QKV
  ushort_t* WoT = (ushort_t*)(ws + (size_t)(6)  * (1 << 20));  // 2 MB
  ushort_t* W1T = (ushort_t*)(ws + (size_t)(8)  * (1 << 20));  // 8 MB  [DF][D]
  ushort_t* W2T = (ushort_t*)(ws + (size_t)(16) * (1 << 20));  // 8 MB  [D][DF]
  ushort_t* xn  = (ushort_t*)(ws + (size_t)(24) * (1 << 20));  // 16 MB [M][D]
  ushort_t* qT  = (ushort_t*)(ws + (size_t)(40) * (1 << 20));  // 16 MB [BH][S][HD]
  ushort_t* kT  = (ushort_t*)(ws + (size_t)(56) * (1 << 20));  // 16 MB
  ushort_t* vT  = (ushort_t*)(ws + (size_t)(72) * (1 << 20));  // 16 MB [BH][HD][S-perm]
  ushort_t* ao  = (ushort_t*)(ws + (size_t)(88) * (1 << 20));  // 16 MB [B,S,H,HD]
  ushort_t* x2b = (ushort_t*)(ws + (size_t)(104)* (1 << 20));  // 16 MB [M][D] bf16 residual
  ushort_t* hb  = (ushort_t*)(ws + (size_t)(136)* (1 << 20));  // 64 MB [M][DF]

  dim3 blk(256), blk5(512);

  // fused transposes (64x64 tiles) + LN1
  PrepArgs pa;
  pa.w4src[0] = Wq; pa.w4src[1] = Wk; pa.w4src[2] = Wv; pa.w4src[3] = Wo;
  pa.w4dst[0] = WqT; pa.w4dst[1] = WkT; pa.w4dst[2] = WvT; pa.w4dst[3] = WoT;
  pa.W1 = W1; pa.W1T = W1T; pa.W2 = W2; pa.W2T = W2T;
  pa.x = x; pa.g = ln1g; pa.b = ln1b; pa.xn = xn;
  prep_kernel<<<3072 + M_, blk, 0, stream>>>(pa);

  // fused QKV projection: 24x64 = 1536 blocks, 8 waves, 2 blocks/CU
  gemmK8<5><<<dim3(3072/128, M_/128), blk5, 0, stream>>>(
      xn, WqT, bq, bk, bv, nullptr, nullptr, nullptr, qT, kT, vT, M_, 3072, D_);
  // attention: 1024 blocks, 4 blocks/CU
  flash_attn<<<dim3(B_*H_, S_/128), blk, 0, stream>>>(qT, kT, vT, ao);
  // output projection + residual -> bf16 x2: 8x64 = 512 blocks
  gemmK8<2><<<dim3(D_/128, M_/128), blk5, 0, stream>>>(
      ao, WoT, bo, nullptr, nullptr, x, nullptr, nullptr, x2b, nullptr, nullptr, M_, D_, D_);
  // LN2 (bf16 in)
  ln_kernel<1><<<M_, blk, 0, stream>>>(x2b, ln2g, ln2b, xn);
  // FFN1: 16x32 = 512 blocks of 256x256, m201-style (R7 best)
  gemm256<3><<<dim3(DF_/256, M_/256), blk5, 0, stream>>>(
      xn, W1T, b1, nullptr, nullptr, nullptr, nullptr, nullptr, hb, nullptr, nullptr, M_, DF_, D_);
  // FFN2: 8x64 = 512 blocks, K=4096
  gemmK8<4><<<dim3(D_/128, M_/128), blk5, 0, stream>>>(
      hb, W2T, b2, nullptr, nullptr, nullptr, x2b, out, nullptr, nullptr, nullptr, M_, D_, DF_);
}